// Round 1
// baseline (906.593 us; speedup 1.0000x reference)
//
#include <hip/hip_runtime.h>

// Problem: B=64, C=16, H=32, W=512, SHIFT=4 (9 offsets), MARGIN=0.15
#define NB 64
#define NC 16
#define NH 32
#define NW 512
#define HW (NH * NW)      // 16384
#define CHW (NC * HW)     // 262144
#define NOFF 9

// ws layout (floats): num_ap[64*9] | num_an[64*9] | cnt_ap[64*9] | cnt_an[64*9]
#define WS_NUM_AP 0
#define WS_NUM_AN 576
#define WS_CNT_AP 1152
#define WS_CNT_AN 1728
#define WS_FLOATS 2304

__device__ __forceinline__ float wave_sum_f(float v) {
#pragma unroll
    for (int o = 32; o > 0; o >>= 1) v += __shfl_down(v, o, 64);
    return v;
}

__device__ __forceinline__ int wave_sum_i(int v) {
#pragma unroll
    for (int o = 32; o > 0; o >>= 1) v += __shfl_down(v, o, 64);
    return v;
}

// grid: (16, 64) blocks of 256 threads. blockIdx.y = batch, blockIdx.x = slice of HW.
// Each block handles 1024 (h,w) positions; each thread 4 positions, all 16 channels.
__global__ __launch_bounds__(256) void num_kernel(
    const float* __restrict__ a, const float* __restrict__ p,
    const float* __restrict__ n, const int* __restrict__ ma,
    const int* __restrict__ mp, const int* __restrict__ mn,
    float* __restrict__ ws)
{
    const int b = blockIdx.y;
    const float* A = a + (size_t)b * CHW;
    const float* P = p + (size_t)b * CHW;
    const float* N = n + (size_t)b * CHW;
    const int* MA = ma + b * HW;
    const int* MP = mp + b * HW;
    const int* MN = mn + b * HW;

    float s_ap[NOFF], s_an[NOFF];
    int c_ap[NOFF], c_an[NOFF];
#pragma unroll
    for (int s = 0; s < NOFF; ++s) { s_ap[s] = 0.f; s_an[s] = 0.f; c_ap[s] = 0; c_an[s] = 0; }

    const int pos_base = blockIdx.x * 1024;
#pragma unroll
    for (int it = 0; it < 4; ++it) {
        const int pos = pos_base + it * 256 + threadIdx.x;   // in [0, HW)
        const int w = pos & (NW - 1);
        const int row = pos - w;                              // h * NW
        const int maV = MA[pos];

        int wi[NOFF];
        unsigned mAp = 0, mAn = 0;
#pragma unroll
        for (int s = 0; s < NOFF; ++s) {
            const int t = (w + 4 - s) & (NW - 1);             // roll(f2, -4+s)[w] = f2[t]
            wi[s] = row + t;
            if (maV && MP[row + t]) { mAp |= (1u << s); c_ap[s]++; }
            if (maV && MN[row + t]) { mAn |= (1u << s); c_an[s]++; }
        }

#pragma unroll 4
        for (int c = 0; c < NC; ++c) {
            const float* Ac = A + c * HW;
            const float* Pc = P + c * HW;
            const float* Nc = N + c * HW;
            const float av = Ac[pos];
#pragma unroll
            for (int s = 0; s < NOFF; ++s) {
                const float pv = Pc[wi[s]];
                const float d1 = av - pv;
                if (mAp & (1u << s)) s_ap[s] += d1 * d1;
                const float nv = Nc[wi[s]];
                const float d2 = av - nv;
                if (mAn & (1u << s)) s_an[s] += d2 * d2;
            }
        }
    }

    // Reduce across the wave; one atomicAdd per wave per counter.
    const int lane = threadIdx.x & 63;
#pragma unroll
    for (int s = 0; s < NOFF; ++s) {
        float v = wave_sum_f(s_ap[s]);
        if (lane == 0) atomicAdd(&ws[WS_NUM_AP + b * NOFF + s], v);
        float u = wave_sum_f(s_an[s]);
        if (lane == 0) atomicAdd(&ws[WS_NUM_AN + b * NOFF + s], u);
        int ci = wave_sum_i(c_ap[s]);
        if (lane == 0) atomicAdd(&ws[WS_CNT_AP + b * NOFF + s], (float)ci);
        int cj = wave_sum_i(c_an[s]);
        if (lane == 0) atomicAdd(&ws[WS_CNT_AN + b * NOFF + s], (float)cj);
    }
}

// 1 block, 64 threads: thread b handles batch b; wave-reduce the mean.
__global__ void finish_kernel(const float* __restrict__ ws, float* __restrict__ out)
{
    const int b = threadIdx.x;   // 0..63
    const float* num_ap = ws + WS_NUM_AP;
    const float* num_an = ws + WS_NUM_AN;
    const float* cnt_ap = ws + WS_CNT_AP;
    const float* cnt_an = ws + WS_CNT_AN;

    float ap = 3.4e38f, an = 3.4e38f;
#pragma unroll
    for (int s = 0; s < NOFF; ++s) {
        ap = fminf(ap, num_ap[b * NOFF + s] / (16.f * cnt_ap[b * NOFF + s] + 0.001f));
        an = fminf(an, num_an[b * NOFF + s] / (16.f * cnt_an[b * NOFF + s] + 0.001f));
    }
    float loss = fmaxf(ap - an + 0.15f, 0.f);
    loss = wave_sum_f(loss);
    if (b == 0) out[0] = loss * (1.0f / 64.f);
}

extern "C" void kernel_launch(void* const* d_in, const int* in_sizes, int n_in,
                              void* d_out, int out_size, void* d_ws, size_t ws_size,
                              hipStream_t stream) {
    const float* a = (const float*)d_in[0];
    const float* p = (const float*)d_in[1];
    const float* n = (const float*)d_in[2];
    const int* ma = (const int*)d_in[3];
    const int* mp = (const int*)d_in[4];
    const int* mn = (const int*)d_in[5];
    float* ws = (float*)d_ws;
    float* out = (float*)d_out;

    // ws is poisoned 0xAA before every timed launch — zero the accumulators.
    hipMemsetAsync(d_ws, 0, WS_FLOATS * sizeof(float), stream);

    num_kernel<<<dim3(16, NB), 256, 0, stream>>>(a, p, n, ma, mp, mn, ws);
    finish_kernel<<<1, 64, 0, stream>>>(ws, out);
}

// Round 2
// 270.391 us; speedup vs baseline: 3.3529x; 3.3529x over previous
//
#include <hip/hip_runtime.h>

// Problem: B=64, C=16, H=32, W=512, SHIFT=4 (9 offsets), MARGIN=0.15
#define NB 64
#define NC 16
#define NH 32
#define NW 512
#define HW (NH * NW)      // 16384
#define CHW (NC * HW)     // 262144
#define NOFF 9

// ws layout (floats): num_ap[64*9] | num_an[64*9] | cnt_ap[64*9] | cnt_an[64*9]
#define WS_NUM_AP 0
#define WS_NUM_AN 576
#define WS_CNT_AP 1152
#define WS_CNT_AN 1728
#define WS_FLOATS 2304

__device__ __forceinline__ float wave_sum_f(float v) {
#pragma unroll
    for (int o = 32; o > 0; o >>= 1) v += __shfl_down(v, o, 64);
    return v;
}

__device__ __forceinline__ int wave_sum_i(int v) {
#pragma unroll
    for (int o = 32; o > 0; o >>= 1) v += __shfl_down(v, o, 64);
    return v;
}

// grid: (16, 64). blockIdx.y = batch. Each thread owns 4 consecutive float4-aligned
// positions; all 9 shifts per channel come from 3 float4 loads (w0-4, w0, w0+4).
__global__ __launch_bounds__(256) void num_kernel(
    const float* __restrict__ a, const float* __restrict__ p,
    const float* __restrict__ n, const int* __restrict__ ma,
    const int* __restrict__ mp, const int* __restrict__ mn,
    float* __restrict__ ws)
{
    const int b = blockIdx.y;
    const int tid = blockIdx.x * 256 + threadIdx.x;  // 0..4095
    const int pos0 = tid * 4;                        // multiple of 4, in [0, HW)
    const int w0 = pos0 & (NW - 1);
    const int row = pos0 - w0;
    const int idxm = row + ((w0 - 4) & (NW - 1));    // aligned float4, row-circular
    const int idxp = row + ((w0 + 4) & (NW - 1));

    const int* MA = ma + b * HW;
    const int* MP = mp + b * HW;
    const int* MN = mn + b * HW;

    // ---- masks: computed once, reused for all 16 channels ----
    int4 mav = *(const int4*)(MA + pos0);
    int4 mp0 = *(const int4*)(MP + idxm);
    int4 mp1 = *(const int4*)(MP + pos0);
    int4 mp2 = *(const int4*)(MP + idxp);
    int4 mn0 = *(const int4*)(MN + idxm);
    int4 mn1 = *(const int4*)(MN + pos0);
    int4 mn2 = *(const int4*)(MN + idxp);

    int mpb[12] = {mp0.x, mp0.y, mp0.z, mp0.w, mp1.x, mp1.y, mp1.z, mp1.w,
                   mp2.x, mp2.y, mp2.z, mp2.w};
    int mnb[12] = {mn0.x, mn0.y, mn0.z, mn0.w, mn1.x, mn1.y, mn1.z, mn1.w,
                   mn2.x, mn2.y, mn2.z, mn2.w};
    int mab[4] = {mav.x, mav.y, mav.z, mav.w};

    unsigned mAp[4], mAn[4];
    int c_ap[NOFF], c_an[NOFF];
#pragma unroll
    for (int s = 0; s < NOFF; ++s) { c_ap[s] = 0; c_an[s] = 0; }
#pragma unroll
    for (int j = 0; j < 4; ++j) {
        unsigned wp = 0, wn = 0;
#pragma unroll
        for (int s = 0; s < NOFF; ++s) {
            // f2 index for (pos0+j, shift s) is buf[j + 8 - s]
            const int k = j + 8 - s;
            if (mab[j] && mpb[k]) { wp |= (1u << s); c_ap[s]++; }
            if (mab[j] && mnb[k]) { wn |= (1u << s); c_an[s]++; }
        }
        mAp[j] = wp; mAn[j] = wn;
    }

    // ---- channel loop ----
    const float* A = a + (size_t)b * CHW;
    const float* P = p + (size_t)b * CHW;
    const float* N = n + (size_t)b * CHW;

    float s_ap[NOFF], s_an[NOFF];
#pragma unroll
    for (int s = 0; s < NOFF; ++s) { s_ap[s] = 0.f; s_an[s] = 0.f; }

#pragma unroll 2
    for (int c = 0; c < NC; ++c) {
        const float* Ac = A + c * HW;
        const float* Pc = P + c * HW;
        const float* Nc = N + c * HW;

        float4 av4 = *(const float4*)(Ac + pos0);
        float pb[12], nb[12];
        *(float4*)&pb[0] = *(const float4*)(Pc + idxm);
        *(float4*)&pb[4] = *(const float4*)(Pc + pos0);
        *(float4*)&pb[8] = *(const float4*)(Pc + idxp);
        *(float4*)&nb[0] = *(const float4*)(Nc + idxm);
        *(float4*)&nb[4] = *(const float4*)(Nc + pos0);
        *(float4*)&nb[8] = *(const float4*)(Nc + idxp);
        float av[4] = {av4.x, av4.y, av4.z, av4.w};

#pragma unroll
        for (int s = 0; s < NOFF; ++s) {
#pragma unroll
            for (int j = 0; j < 4; ++j) {
                const int k = j + 8 - s;
                const float d = av[j] - pb[k];
                const float dm = ((mAp[j] >> s) & 1u) ? d : 0.f;
                s_ap[s] = fmaf(d, dm, s_ap[s]);
                const float e = av[j] - nb[k];
                const float em = ((mAn[j] >> s) & 1u) ? e : 0.f;
                s_an[s] = fmaf(e, em, s_an[s]);
            }
        }
    }

    // ---- reduce across the wave; one atomicAdd per wave per counter ----
    const int lane = threadIdx.x & 63;
#pragma unroll
    for (int s = 0; s < NOFF; ++s) {
        float v = wave_sum_f(s_ap[s]);
        if (lane == 0) atomicAdd(&ws[WS_NUM_AP + b * NOFF + s], v);
        float u = wave_sum_f(s_an[s]);
        if (lane == 0) atomicAdd(&ws[WS_NUM_AN + b * NOFF + s], u);
        int ci = wave_sum_i(c_ap[s]);
        if (lane == 0) atomicAdd(&ws[WS_CNT_AP + b * NOFF + s], (float)ci);
        int cj = wave_sum_i(c_an[s]);
        if (lane == 0) atomicAdd(&ws[WS_CNT_AN + b * NOFF + s], (float)cj);
    }
}

// 1 block, 64 threads: thread b handles batch b; wave-reduce the mean.
__global__ void finish_kernel(const float* __restrict__ ws, float* __restrict__ out)
{
    const int b = threadIdx.x;   // 0..63
    const float* num_ap = ws + WS_NUM_AP;
    const float* num_an = ws + WS_NUM_AN;
    const float* cnt_ap = ws + WS_CNT_AP;
    const float* cnt_an = ws + WS_CNT_AN;

    float ap = 3.4e38f, an = 3.4e38f;
#pragma unroll
    for (int s = 0; s < NOFF; ++s) {
        ap = fminf(ap, num_ap[b * NOFF + s] / (16.f * cnt_ap[b * NOFF + s] + 0.001f));
        an = fminf(an, num_an[b * NOFF + s] / (16.f * cnt_an[b * NOFF + s] + 0.001f));
    }
    float loss = fmaxf(ap - an + 0.15f, 0.f);
    loss = wave_sum_f(loss);
    if (b == 0) out[0] = loss * (1.0f / 64.f);
}

extern "C" void kernel_launch(void* const* d_in, const int* in_sizes, int n_in,
                              void* d_out, int out_size, void* d_ws, size_t ws_size,
                              hipStream_t stream) {
    const float* a = (const float*)d_in[0];
    const float* p = (const float*)d_in[1];
    const float* n = (const float*)d_in[2];
    const int* ma = (const int*)d_in[3];
    const int* mp = (const int*)d_in[4];
    const int* mn = (const int*)d_in[5];
    float* ws = (float*)d_ws;
    float* out = (float*)d_out;

    // ws is poisoned 0xAA before every timed launch — zero the accumulators.
    hipMemsetAsync(d_ws, 0, WS_FLOATS * sizeof(float), stream);

    num_kernel<<<dim3(16, NB), 256, 0, stream>>>(a, p, n, ma, mp, mn, ws);
    finish_kernel<<<1, 64, 0, stream>>>(ws, out);
}